// Round 7
// baseline (548.101 us; speedup 1.0000x reference)
//
#include <hip/hip_runtime.h>
#include <math.h>
#include <limits.h>

#define TPB   256
#define MAXT  2048
#define TPAD  64            // pad so unconditional reads past e stay in-bounds
#define MAXK  1024
#define MAXW  29            // fast-path span width (W=30 -> w<=29)
#define WIN   256           // greedy: candidates per producer window
#define RSLOT 8             // greedy: ring slots (power of 2)

#define VOL(x) (*(volatile int*)&(x))

// One block per 256 items: nT = ceil(N/256) = 240 blocks, all co-resident
// (1 block/CU needs only 256 thr + ~50KB LDS). Grid barriers are safe.
struct SMem {
  union {
    unsigned h[1024];                     // P0: 4 pass histograms
    struct {                              // radix pass phases
      unsigned wcnt[4][256];              // [wave][digit] (also P1 scan bufs)
      unsigned baseL[256];
    } pass;
    struct {                              // greedy phase (block 0 only)
      unsigned tabP[MAXT + TPAD];         // hi16=e2s(enc), lo16=s2e+1
      int2 tab[MAXT + TPAD];              // authoritative: .x=s2e, .y=e2s
      unsigned long long acc[MAXK];
      unsigned long long ring[RSLOT][WIN];
      int slotCnt[RSLOT];                 // -1 = empty
      int slotVer[RSLOT];                 // gAcc snapshot at producer precheck
      int lastCons, gDone, gAcc, ticket, gcntF;
    } g;
  };
};

__device__ inline void gbar(unsigned* ctr, int idx, unsigned nblk) {
  __syncthreads();
  if (threadIdx.x == 0) {
    __threadfence();
    atomicAdd(&ctr[idx], 1u);
    while (atomicAdd(&ctr[idx], 0u) < nblk) { __builtin_amdgcn_s_sleep(8); }
    __threadfence();
  }
  __syncthreads();
}

__device__ inline bool cross_check(const unsigned* tabP, int cs, int ce) {
  int w = ce - cs;
  bool crossed = false;
  #pragma unroll
  for (int off = 0; off <= MAXW; ++off) {
    unsigned tv = tabP[cs + off];
    crossed |= ((off >= 1) & (off <= w) & ((tv & 0xFFFFu) > (unsigned)(ce + 1)))
             | ((off < w) & ((tv >> 16) < (unsigned)cs));
  }
  for (int off = MAXW + 1; off <= w; ++off) {     // generic fallback (unused)
    unsigned tv = tabP[cs + off];
    crossed |= ((tv & 0xFFFFu) > (unsigned)(ce + 1));
    if (off < w) crossed |= ((tv >> 16) < (unsigned)cs);
  }
  return crossed;
}

__global__ void __launch_bounds__(TPB, 1) mega_kernel(
    const int2* __restrict__ spans2,
    const float* __restrict__ scores, const float* __restrict__ mask,
    const int* __restrict__ tnum_p, const int* __restrict__ keep_p,
    float* __restrict__ out, int N, int nT,
    unsigned* ctr, unsigned* ghist, unsigned* tileCnt,
    unsigned long long* kvA, unsigned long long* kvB, int* idxOut) {
  __shared__ SMem s;
  const int tid = threadIdx.x;
  const int lane = tid & 63;
  const int wave = tid >> 6;
  const unsigned long long lower = (1ull << lane) - 1ull;

  // ---------------- P0: build packed keys + all 4 histograms ----------------
  for (int j = tid; j < 1024; j += TPB) s.h[j] = 0;
  __syncthreads();
  {
    int i = blockIdx.x * TPB + tid;
    if (i < N) {
      float kf = scores[i] + logf(mask[i]);          // mask==1 -> +0 exact
      unsigned u = __float_as_uint(kf);
      u = (u & 0x80000000u) ? ~u : (u | 0x80000000u);
      u = ~u;                                        // descending order
      kvA[i] = ((unsigned long long)u << 32) | (unsigned)i;
      atomicAdd(&s.h[(u & 255u)], 1u);
      atomicAdd(&s.h[256 + ((u >> 8) & 255u)], 1u);
      atomicAdd(&s.h[512 + ((u >> 16) & 255u)], 1u);
      atomicAdd(&s.h[768 + (u >> 24)], 1u);
    }
  }
  __syncthreads();
  for (int j = tid; j < 1024; j += TPB)
    if (s.h[j]) atomicAdd(&ghist[j], s.h[j]);
  gbar(ctr, 0, nT);

  // ---------------- P1: block 0 scans digit bases (4x256 exclusive) ---------
  if (blockIdx.x == 0) {
    for (int p = 0; p < 4; ++p) {
      unsigned v = ghist[p * 256 + tid];
      unsigned* A = s.pass.wcnt[0];
      unsigned* B = s.pass.wcnt[1];
      A[tid] = v;
      __syncthreads();
      for (int off = 1; off < 256; off <<= 1) {
        B[tid] = A[tid] + ((tid >= off) ? A[tid - off] : 0u);
        __syncthreads();
        unsigned* t = A; A = B; B = t;
      }
      ghist[p * 256 + tid] = A[tid] - v;
      __syncthreads();
    }
  }
  gbar(ctr, 1, nT);

  // ---------------- 4 rank/scatter radix passes (1 round/block) -------------
  for (int p = 0; p < 4; ++p) {
    const unsigned long long* src = (p & 1) ? kvB : kvA;
    unsigned long long*       dst = (p & 1) ? kvA : kvB;
    const int shift = 8 * p;

    s.pass.wcnt[0][tid] = 0; s.pass.wcnt[1][tid] = 0;
    s.pass.wcnt[2][tid] = 0; s.pass.wcnt[3][tid] = 0;
    __syncthreads();
    int i = blockIdx.x * TPB + tid;
    bool v = (i < N);
    unsigned long long kv = v ? src[i] : 0ull;
    unsigned d = ((unsigned)(kv >> 32) >> shift) & 255u;
    unsigned long long mm = __ballot(v);      // stable same-digit lane mask
    #pragma unroll
    for (int b = 0; b < 8; ++b) {
      unsigned long long bb = __ballot((d >> b) & 1u);
      mm &= ((d >> b) & 1u) ? bb : ~bb;
    }
    int rank = (int)__popcll(mm & lower);
    if (v && rank == 0) s.pass.wcnt[wave][d] = (unsigned)__popcll(mm);
    __syncthreads();
    // thread 'tid' scans digit 'tid' across 4 waves; run = block digit total
    unsigned run = 0;
    #pragma unroll
    for (int w2 = 0; w2 < 4; ++w2) {
      unsigned c = s.pass.wcnt[w2][tid];
      s.pass.wcnt[w2][tid] = run;
      run += c;
    }
    tileCnt[blockIdx.x * 256 + tid] = run;
    __syncthreads();
    unsigned myoff = v ? (s.pass.wcnt[wave][d] + (unsigned)rank) : 0u;
    gbar(ctr, 2 + 2 * p, nT);

    // redundant per-block tile prefix (coalesced rows)
    unsigned baseacc = ghist[p * 256 + tid];
    for (int t = 0; t < blockIdx.x; ++t)
      baseacc += tileCnt[t * 256 + tid];
    s.pass.baseL[tid] = baseacc;
    __syncthreads();
    if (v) {
      unsigned pos = s.pass.baseL[d] + myoff;
      if (p < 3) dst[pos] = kv;
      else       idxOut[pos] = (int)(unsigned)kv;
    }
    gbar(ctr, 3 + 2 * p, nT);   // final barrier also publishes idxOut
  }

  if (blockIdx.x != 0) return;

  // ================= Greedy phase (block 0: 1 consumer + 3 producer waves) ==
  const int* order = idxOut;
  const int T  = tnum_p[0];
  const int k0 = keep_p[0];
  const int k  = (k0 < MAXK) ? k0 : MAXK;
  const int nW = (N + WIN - 1) / WIN;

  for (int t = tid; t < MAXT + TPAD; t += TPB) {
    s.g.tab[t] = make_int2(-1, INT_MAX);
    s.g.tabP[t] = 0xFFFF0000u;            // s2e+1 = 0, e2s_enc = 0xFFFF
  }
  if (tid < RSLOT) s.g.slotCnt[tid] = -1;
  if (tid == 0) {
    s.g.lastCons = 0; s.g.gDone = 0; s.g.gAcc = 0; s.g.ticket = 0; s.g.gcntF = 0;
  }
  __syncthreads();

  if (wave == 0) {
    // ---------------- CONSUMER ----------------
    int cnt = 0;
    for (int w = 0; w < nW && cnt < k; ++w) {
      int sl = w & (RSLOT - 1);
      int ns;
      while ((ns = VOL(s.g.slotCnt[sl])) < 0) { __builtin_amdgcn_s_sleep(1); }
      __threadfence_block();
      int sver = VOL(s.g.slotVer[sl]);
      for (int g = 0; g < ns && cnt < k; g += 64) {
        int m = ns - g; if (m > 64) m = 64;
        bool act = lane < m;
        unsigned long long pk = act ? s.g.ring[sl][g + lane] : 0ull;
        int gs = (int)(pk >> 48);
        int ge = (int)((pk >> 32) & 0xFFFFu);
        int gc = (int)(unsigned)pk;
        bool pre = act;
        if (cnt != sver)                    // tables advanced since precheck
          pre = act && !cross_check(s.g.tabP, gs, ge);
        unsigned long long rem = __ballot(pre);
        if (rem == 0ull) continue;
        // acceptance-broadcast serial greedy: cost ~ #acceptances, not #survivors
        unsigned long long accm = 0ull;
        int cnt0g = cnt;
        while (rem && cnt < k) {
          int j = __ffsll((long long)rem) - 1;
          rem &= rem - 1;
          accm |= 1ull << j;
          cnt++;
          int sa = __shfl(gs, j), ea = __shfl(ge, j);
          bool mycross = (gs < sa && sa <= ge && ea > ge) ||
                         (sa < gs && gs <= ea && ea < ge);
          rem &= ~__ballot(mycross);        // bulk-reject crossers of (sa,ea)
        }
        bool accme = ((accm >> lane) & 1ull) != 0ull;
        if (accme) {                        // acceptance order == lane order
          int rnk = (int)__popcll(accm & lower);
          s.g.acc[cnt0g + rnk] =
              ((unsigned long long)(unsigned)(gs * T + ge) << 32) | (unsigned)gc;
          atomicMax(&s.g.tab[gs].x, ge);
          atomicMin(&s.g.tab[ge].y, gs);
        }
        if (accme) {    // same-wave DS in-order: reads see all lanes' atomics
          int2 tv = s.g.tab[gs];
          s.g.tabP[gs] = ((unsigned)(tv.y > 65535 ? 65535 : tv.y) << 16)
                       | (unsigned)(tv.x + 1);
          int2 tv2 = s.g.tab[ge];
          s.g.tabP[ge] = ((unsigned)(tv2.y > 65535 ? 65535 : tv2.y) << 16)
                       | (unsigned)(tv2.x + 1);
        }
        if (lane == 0 && accm) { __threadfence_block(); VOL(s.g.gAcc) = cnt; }
      }
      if (lane == 0) {
        __threadfence_block();              // ring reads done before reuse
        VOL(s.g.slotCnt[sl]) = -1;
        VOL(s.g.lastCons) = w + 1;
      }
    }
    if (lane == 0) {
      VOL(s.g.gcntF) = cnt; __threadfence_block(); VOL(s.g.gDone) = 1;
    }
  } else {
    // ---------------- PRODUCERS (waves 1-3) ----------------
    for (;;) {
      int myw = 0;
      if (lane == 0) myw = atomicAdd(&s.g.ticket, 1);
      myw = __shfl(myw, 0);
      if (myw >= nW) break;
      int sl = myw & (RSLOT - 1);
      bool abort = false;
      while (VOL(s.g.lastCons) < myw - (RSLOT - 1)) {   // wait slot reusable
        if (VOL(s.g.gDone)) { abort = true; break; }
        __builtin_amdgcn_s_sleep(1);
      }
      if (abort || VOL(s.g.gDone)) break;
      int sver = VOL(s.g.gAcc);
      __threadfence_block();                // gAcc read before tabP reads
      int c0 = myw * WIN;
      int cand[4], cs4[4], ce4[4];
      #pragma unroll
      for (int r = 0; r < 4; ++r) {
        int i = c0 + r * 64 + lane;
        cand[r] = (i < N) ? order[i] : -1;
      }
      #pragma unroll
      for (int r = 0; r < 4; ++r) {
        cs4[r] = 0; ce4[r] = 0;
        if (cand[r] >= 0) { int2 sp = spans2[cand[r]]; cs4[r] = sp.x; ce4[r] = sp.y; }
      }
      int ns = 0;
      #pragma unroll
      for (int r = 0; r < 4; ++r) {
        bool ok = (cand[r] >= 0) && !cross_check(s.g.tabP, cs4[r], ce4[r]);
        unsigned long long bal = __ballot(ok);
        if (ok) {
          int pos = ns + (int)__popcll(bal & lower);
          s.g.ring[sl][pos] = ((unsigned long long)(unsigned)cs4[r] << 48)
                            | ((unsigned long long)(unsigned)ce4[r] << 32)
                            | (unsigned)cand[r];
        }
        ns += (int)__popcll(bal);
      }
      if (lane == 0) {
        __threadfence_block();              // ring data before flag
        VOL(s.g.slotVer[sl]) = sver;
        VOL(s.g.slotCnt[sl]) = ns;          // publish
      }
    }
  }
  __syncthreads();
  int cnt = s.g.gcntF;

  // ---- bitonic ascending sort of acc[0..cnt) by (s*T+e, cand) ----
  int M = 2;
  while (M < cnt) M <<= 1;
  for (int j = tid; j < M; j += TPB)
    if (j >= cnt) s.g.acc[j] = ~0ull;
  __syncthreads();
  for (int kk = 2; kk <= M; kk <<= 1) {
    for (int jj = kk >> 1; jj > 0; jj >>= 1) {
      for (int i3 = tid; i3 < M; i3 += TPB) {
        int ixj = i3 ^ jj;
        if (ixj > i3) {
          unsigned long long a = s.g.acc[i3], b = s.g.acc[ixj];
          bool up = ((i3 & kk) == 0);
          if ((a > b) == up) { s.g.acc[i3] = b; s.g.acc[ixj] = a; }
        }
      }
      __syncthreads();
    }
  }

  // ---- epilogue: scores | idx | spans | valid, all f32 ----
  for (int j = tid; j < k0; j += TPB) {
    if (j < cnt) {
      int cand = (int)(s.g.acc[j] & 0xFFFFFFFFu);
      int2 sp = spans2[cand];
      out[j]                  = scores[cand];
      out[k0 + j]             = (float)cand;
      out[2 * k0 + 2 * j]     = (float)sp.x;
      out[2 * k0 + 2 * j + 1] = (float)sp.y;
      out[4 * k0 + j]         = 1.0f;
    } else {
      out[j]                  = 0.0f;
      out[k0 + j]             = 0.0f;
      out[2 * k0 + 2 * j]     = 0.0f;
      out[2 * k0 + 2 * j + 1] = 0.0f;
      out[4 * k0 + j]         = 0.0f;
    }
  }
}

extern "C" void kernel_launch(void* const* d_in, const int* in_sizes, int n_in,
                              void* d_out, int out_size, void* d_ws, size_t ws_size,
                              hipStream_t stream) {
  const int*   spans  = (const int*)d_in[0];
  const float* scores = (const float*)d_in[1];
  const float* mask   = (const float*)d_in[2];
  const int*   tnum   = (const int*)d_in[3];
  const int*   keep   = (const int*)d_in[4];
  const int N = in_sizes[1];
  const int nT = (N + TPB - 1) / TPB;   // 240 for N=61440; must stay <=256
                                        // (1 block/CU co-residency for gbar)

  // ws: kvA[N] u64 | kvB[N] u64 | ctr[32] | ghist[1024] | tileCnt[nT*256] | idxOut[N]
  char* p = (char*)d_ws;
  unsigned long long* kvA = (unsigned long long*)p;  p += (size_t)N * 8;
  unsigned long long* kvB = (unsigned long long*)p;  p += (size_t)N * 8;
  unsigned* ctr     = (unsigned*)p;                  p += 32 * 4;
  unsigned* ghist   = (unsigned*)p;                  p += 1024 * 4;
  unsigned* tileCnt = (unsigned*)p;                  p += (size_t)nT * 256 * 4;
  int*      idxOut  = (int*)p;
  float*    out     = (float*)d_out;

  hipMemsetAsync(ctr, 0, (32 + 1024) * sizeof(unsigned), stream);

  mega_kernel<<<nT, TPB, 0, stream>>>(
      (const int2*)spans, scores, mask, tnum, keep, out, N, nT,
      ctr, ghist, tileCnt, kvA, kvB, idxOut);
}

// Round 8
// 336.059 us; speedup vs baseline: 1.6310x; 1.6310x over previous
//
#include <hip/hip_runtime.h>
#include <math.h>
#include <limits.h>

#define TPB   256
#define TILE  1024          // sort: items per block-tile (256 thr x 4 rounds)
#define RNDS  4
#define MAXT  2048
#define TPAD  64            // pad so unconditional reads past e stay in-bounds
#define MAXK  1024
#define MAXW  29            // fast-path span width (W=30 -> w<=29)
#define CSTR  32            // barrier counter stride in words (128B slots)

// ===========================================================================
// Grid barrier, contention-fixed: 128B-padded counter per barrier, arrive is
// one RMW, polling is relaxed agent-scope LOADS (no RMW serialization).
// SAFE: grid (60 blocks) fully co-resident on 256 CUs.
// ===========================================================================
__device__ inline void gbar(unsigned* ctr, int idx, unsigned nblk) {
  __syncthreads();
  if (threadIdx.x == 0) {
    unsigned* c = ctr + idx * CSTR;
    __threadfence();
    atomicAdd(c, 1u);
    while (__hip_atomic_load(c, __ATOMIC_RELAXED, __HIP_MEMORY_SCOPE_AGENT)
           < nblk)
      __builtin_amdgcn_s_sleep(2);
    __threadfence();
  }
  __syncthreads();
}

// ===========================================================================
// Kernel A: fused key-build + 4-pass LSD radix argsort (60 blocks).
// Key+payload packed in one u64 (key<<32|idx).
// ===========================================================================
struct SortSM {
  union {
    unsigned h[4 * 256];
    struct {
      unsigned wcnt[4][256];
      unsigned runCnt[256];
      unsigned baseL[256];
    } pass;
  };
};

__global__ void __launch_bounds__(TPB, 1) sort_kernel(
    const float* __restrict__ scores, const float* __restrict__ mask,
    int N, int nT, unsigned* ctr, unsigned* ghist, unsigned* tileCnt,
    unsigned long long* kvA, unsigned long long* kvB, int* idxOut) {
  __shared__ SortSM s;
  const int tid = threadIdx.x;
  const int lane = tid & 63;
  const int wave = tid >> 6;

  // ---- P0: build packed keys + all 4 histograms in one read ----
  for (int j = tid; j < 1024; j += TPB) s.h[j] = 0;
  __syncthreads();
  {
    const int tile0 = blockIdx.x * TILE;
    for (int r = 0; r < RNDS; ++r) {
      int i = tile0 + r * 256 + tid;
      if (i < N) {
        float kf = scores[i] + logf(mask[i]);          // mask==1 -> +0 exact
        unsigned u = __float_as_uint(kf);
        u = (u & 0x80000000u) ? ~u : (u | 0x80000000u);
        u = ~u;                                        // descending order
        kvA[i] = ((unsigned long long)u << 32) | (unsigned)i;
        atomicAdd(&s.h[(u & 255u)], 1u);
        atomicAdd(&s.h[256 + ((u >> 8) & 255u)], 1u);
        atomicAdd(&s.h[512 + ((u >> 16) & 255u)], 1u);
        atomicAdd(&s.h[768 + (u >> 24)], 1u);
      }
    }
    __syncthreads();
    for (int j = tid; j < 1024; j += TPB)
      if (s.h[j]) atomicAdd(&ghist[j], s.h[j]);
  }
  gbar(ctr, 0, nT);

  // ---- P1: block 0 scans digit bases (4x256 exclusive) ----
  if (blockIdx.x == 0) {
    for (int p = 0; p < 4; ++p) {
      unsigned v = ghist[p * 256 + tid];
      unsigned* A = s.pass.wcnt[0];
      unsigned* B = s.pass.wcnt[1];
      A[tid] = v;
      __syncthreads();
      for (int off = 1; off < 256; off <<= 1) {
        B[tid] = A[tid] + ((tid >= off) ? A[tid - off] : 0u);
        __syncthreads();
        unsigned* t = A; A = B; B = t;
      }
      ghist[p * 256 + tid] = A[tid] - v;
      __syncthreads();
    }
  }
  gbar(ctr, 1, nT);

  // ---- 4 fused rank/scatter radix passes ----
  for (int p = 0; p < 4; ++p) {
    const unsigned long long* src = (p & 1) ? kvB : kvA;
    unsigned long long*       dst = (p & 1) ? kvA : kvB;
    const int shift = 8 * p;
    const int tile0 = blockIdx.x * TILE;

    s.pass.runCnt[tid] = 0;
    unsigned long long mykv[RNDS]; unsigned mypos[RNDS]; bool myval[RNDS];
    #pragma unroll
    for (int r = 0; r < RNDS; ++r) {
      __syncthreads();
      s.pass.wcnt[0][tid] = 0; s.pass.wcnt[1][tid] = 0;
      s.pass.wcnt[2][tid] = 0; s.pass.wcnt[3][tid] = 0;
      __syncthreads();
      int i = tile0 + r * 256 + tid;
      bool v = (i < N);
      unsigned long long kv = v ? src[i] : 0ull;
      unsigned d = ((unsigned)(kv >> 32) >> shift) & 255u;
      unsigned long long mm = __ballot(v);    // stable same-digit lane mask
      #pragma unroll
      for (int b = 0; b < 8; ++b) {
        unsigned long long bb = __ballot((d >> b) & 1u);
        mm &= ((d >> b) & 1u) ? bb : ~bb;
      }
      int rank = (int)__popcll(mm & ((1ull << lane) - 1ull));
      if (v && rank == 0) s.pass.wcnt[wave][d] = (unsigned)__popcll(mm);
      __syncthreads();
      unsigned run0 = s.pass.runCnt[tid];
      unsigned run = 0;
      #pragma unroll
      for (int w2 = 0; w2 < 4; ++w2) {
        unsigned c = s.pass.wcnt[w2][tid];
        s.pass.wcnt[w2][tid] = run0 + run;
        run += c;
      }
      s.pass.runCnt[tid] = run0 + run;
      __syncthreads();
      mykv[r] = kv; myval[r] = v;
      mypos[r] = v ? (s.pass.wcnt[wave][d] + (unsigned)rank) : 0u;
    }
    __syncthreads();
    tileCnt[blockIdx.x * 256 + tid] = s.pass.runCnt[tid];
    gbar(ctr, 2 + 2 * p, nT);

    // redundant per-block tile prefix (coalesced rows)
    unsigned baseacc = ghist[p * 256 + tid];
    for (int t = 0; t < blockIdx.x; ++t)
      baseacc += tileCnt[t * 256 + tid];
    s.pass.baseL[tid] = baseacc;
    __syncthreads();
    #pragma unroll
    for (int r = 0; r < RNDS; ++r) {
      if (myval[r]) {
        unsigned d = ((unsigned)(mykv[r] >> 32) >> shift) & 255u;
        unsigned pos = s.pass.baseL[d] + mypos[r];
        if (p < 3) dst[pos] = mykv[r];
        else       idxOut[pos] = (int)(unsigned)mykv[r];
      }
    }
    if (p < 3) gbar(ctr, 3 + 2 * p, nT);
  }
}

// ===========================================================================
// Kernel B: batch-synchronous greedy (1 block) with acceptance-broadcast
// resolution: cost scales with acceptances (~k), not survivors. Round-5
// skeleton (proven); round-7 consumer loop (proven).
// ===========================================================================
__device__ inline bool cross_check(const unsigned* tabP, int cs, int ce) {
  int w = ce - cs;
  bool crossed = false;
  #pragma unroll
  for (int off = 0; off <= MAXW; ++off) {
    unsigned tv = tabP[cs + off];
    crossed |= ((off >= 1) & (off <= w) & ((tv & 0xFFFFu) > (unsigned)(ce + 1)))
             | ((off < w) & ((tv >> 16) < (unsigned)cs));
  }
  for (int off = MAXW + 1; off <= w; ++off) {     // generic fallback (unused)
    unsigned tv = tabP[cs + off];
    crossed |= ((tv & 0xFFFFu) > (unsigned)(ce + 1));
    if (off < w) crossed |= ((tv >> 16) < (unsigned)cs);
  }
  return crossed;
}

__global__ void __launch_bounds__(TPB, 1) greedy_kernel(
    const int2* __restrict__ spans2,
    const float* __restrict__ scores, const int* __restrict__ order,
    const int* __restrict__ tnum_p, const int* __restrict__ keep_p,
    float* __restrict__ out, int N) {
  __shared__ unsigned tabP[MAXT + TPAD];  // hi16 = e2s(enc), lo16 = s2e+1
  __shared__ int2 tab[MAXT + TPAD];       // authoritative: .x=s2e, .y=e2s
  __shared__ unsigned long long acc[MAXK];
  __shared__ unsigned long long surv[TPB];
  __shared__ int wvs[4];
  __shared__ int gcnt;

  const int tid = threadIdx.x;
  const int lane = tid & 63;
  const int wave = tid >> 6;
  const int T  = tnum_p[0];
  const int k0 = keep_p[0];
  const int k  = (k0 < MAXK) ? k0 : MAXK;
  const unsigned long long lower = (1ull << lane) - 1ull;

  for (int t = tid; t < MAXT + TPAD; t += TPB) {
    tab[t] = make_int2(-1, INT_MAX);
    tabP[t] = 0xFFFF0000u;               // s2e+1 = 0, e2s_enc = 0xFFFF
  }
  if (tid == 0) gcnt = 0;
  __syncthreads();

  // two-deep prefetch, 256-wide
  int cc = -1, cs = 0, ce = 0, nc = -1;
  if (tid < N) cc = order[tid];
  if (TPB + tid < N) nc = order[TPB + tid];
  if (cc >= 0) { int2 sp = spans2[cc]; cs = sp.x; ce = sp.y; }

  int cnt = 0;
  for (int c0 = 0; c0 < N && cnt < k; c0 += TPB) {
    int pc = nc, ps = 0, pe = 0;
    if (pc >= 0) { int2 sp = spans2[pc]; ps = sp.x; pe = sp.y; }
    int i2 = c0 + 2 * TPB + tid;
    nc = (i2 < N) ? order[i2] : -1;

    // ---- parallel pre-check vs tables (monotone -> speculative-safe) ----
    bool ok = (cc >= 0) && !cross_check(tabP, cs, ce);

    // ---- order-preserving survivor compression -> LDS ----
    unsigned long long bal = __ballot(ok);
    if (lane == 0) wvs[wave] = (int)__popcll(bal);
    __syncthreads();
    int wbase = 0;
    for (int w2 = 0; w2 < wave; ++w2) wbase += wvs[w2];
    int ns = wvs[0] + wvs[1] + wvs[2] + wvs[3];
    if (ok) {
      int pos = wbase + (int)__popcll(bal & lower);
      surv[pos] = ((unsigned long long)(unsigned)cs << 48)
                | ((unsigned long long)(unsigned)ce << 32)
                | (unsigned)cc;
    }
    __syncthreads();

    // ---- wave-0 resolution: acceptance-broadcast with bulk-reject ----
    if (tid < 64) {
      bool dirty = false;      // any in-batch acceptance since pre-check?
      for (int g = 0; g < ns && cnt < k; g += 64) {
        int m = ns - g; if (m > 64) m = 64;
        bool act = lane < m;
        unsigned long long pk = act ? surv[g + lane] : 0ull;
        int gs = (int)(pk >> 48);
        int ge = (int)((pk >> 32) & 0xFFFFu);
        int gc = (int)(unsigned)pk;
        bool pre = act;
        if (dirty)                         // re-check only if tables advanced
          pre = act && !cross_check(tabP, gs, ge);
        unsigned long long rem = __ballot(pre);
        if (rem == 0ull) continue;
        // serial greedy, cost ~ #acceptances: accept first survivor, evict
        // all its crossers with ONE ballot, repeat.
        unsigned long long accm = 0ull;
        int cnt0g = cnt;
        while (rem && cnt < k) {
          int j = __ffsll((long long)rem) - 1;
          rem &= rem - 1;
          accm |= 1ull << j;
          cnt++;
          int sa = __shfl(gs, j), ea = __shfl(ge, j);
          bool mycross = (gs < sa && sa <= ge && ea > ge) ||
                         (sa < gs && gs <= ea && ea < ge);
          rem &= ~__ballot(mycross);       // bulk-reject crossers of (sa,ea)
        }
        bool accme = ((accm >> lane) & 1ull) != 0ull;
        if (accme) {                       // acceptance order == lane order
          int rnk = (int)__popcll(accm & lower);
          acc[cnt0g + rnk] =
              ((unsigned long long)(unsigned)(gs * T + ge) << 32) | (unsigned)gc;
          atomicMax(&tab[gs].x, ge);
          atomicMin(&tab[ge].y, gs);
        }
        if (accme) {    // same-wave DS in-order: reads see all lanes' atomics
          int2 tv = tab[gs];
          tabP[gs] = ((unsigned)(tv.y > 65535 ? 65535 : tv.y) << 16)
                   | (unsigned)(tv.x + 1);
          int2 tv2 = tab[ge];
          tabP[ge] = ((unsigned)(tv2.y > 65535 ? 65535 : tv2.y) << 16)
                   | (unsigned)(tv2.x + 1);
        }
        if (accm) dirty = true;
      }
      if (lane == 0) gcnt = cnt;
    }
    __syncthreads();
    cnt = gcnt;
    cc = pc; cs = ps; ce = pe;
  }

  // ---- bitonic ascending sort of acc[0..cnt) by (s*T+e, cand) ----
  int M = 2;
  while (M < cnt) M <<= 1;
  for (int j = tid; j < M; j += TPB)
    if (j >= cnt) acc[j] = ~0ull;
  __syncthreads();
  for (int kk = 2; kk <= M; kk <<= 1) {
    for (int jj = kk >> 1; jj > 0; jj >>= 1) {
      for (int i3 = tid; i3 < M; i3 += TPB) {
        int ixj = i3 ^ jj;
        if (ixj > i3) {
          unsigned long long a = acc[i3], b = acc[ixj];
          bool up = ((i3 & kk) == 0);
          if ((a > b) == up) { acc[i3] = b; acc[ixj] = a; }
        }
      }
      __syncthreads();
    }
  }

  // ---- epilogue: scores | idx | spans | valid, all f32 ----
  for (int j = tid; j < k0; j += TPB) {
    if (j < cnt) {
      int cand = (int)(acc[j] & 0xFFFFFFFFu);
      int2 sp = spans2[cand];
      out[j]                  = scores[cand];
      out[k0 + j]             = (float)cand;
      out[2 * k0 + 2 * j]     = (float)sp.x;
      out[2 * k0 + 2 * j + 1] = (float)sp.y;
      out[4 * k0 + j]         = 1.0f;
    } else {
      out[j]                  = 0.0f;
      out[k0 + j]             = 0.0f;
      out[2 * k0 + 2 * j]     = 0.0f;
      out[2 * k0 + 2 * j + 1] = 0.0f;
      out[4 * k0 + j]         = 0.0f;
    }
  }
}

extern "C" void kernel_launch(void* const* d_in, const int* in_sizes, int n_in,
                              void* d_out, int out_size, void* d_ws, size_t ws_size,
                              hipStream_t stream) {
  const int*   spans  = (const int*)d_in[0];
  const float* scores = (const float*)d_in[1];
  const float* mask   = (const float*)d_in[2];
  const int*   tnum   = (const int*)d_in[3];
  const int*   keep   = (const int*)d_in[4];
  const int N = in_sizes[1];
  const int nT = (N + TILE - 1) / TILE;   // 60 for N=61440

  // ws: kvA[N] u64 | kvB[N] u64 | ctr[16*CSTR] | ghist[1024] | tileCnt | idxOut
  char* p = (char*)d_ws;
  unsigned long long* kvA = (unsigned long long*)p;  p += (size_t)N * 8;
  unsigned long long* kvB = (unsigned long long*)p;  p += (size_t)N * 8;
  unsigned* ctr     = (unsigned*)p;                  p += 16 * CSTR * 4;
  unsigned* ghist   = (unsigned*)p;                  p += 1024 * 4;
  unsigned* tileCnt = (unsigned*)p;                  p += (size_t)nT * 256 * 4;
  int*      idxOut  = (int*)p;
  float*    out     = (float*)d_out;

  hipMemsetAsync(ctr, 0, (16 * CSTR + 1024) * sizeof(unsigned), stream);

  sort_kernel<<<nT, TPB, 0, stream>>>(scores, mask, N, nT, ctr, ghist,
                                      tileCnt, kvA, kvB, idxOut);
  greedy_kernel<<<1, TPB, 0, stream>>>((const int2*)spans, scores,
                                       idxOut, tnum, keep, out, N);
}